// Round 6
// baseline (143.463 us; speedup 1.0000x reference)
//
#include <hip/hip_runtime.h>
#include <cstdint>

#define R_SPHEREf 3.0f
#define NEARf 0.0f
#define FARf 100.0f
#define SECANT_STEPS 4
#define EPSf 1e-4f
#define R0f 1.0f
#define Hh 64
#define Lc 4
#define Sn 64

// tanh via: w2*tanh(x) = w2 - 2*w2 / (exp2(C*x)+1),  C = 2*log2(e).
// C pre-folded into (A2,B2); -2*w2 stored as m2w2; Sum(w2)+b2+R0 in sbase.
// Saturation exact: exp2->inf => rcp->0; exp2->0 => r=1. No NaN path.
#define C_HI 2.88539004325866699f
#define C_LO 3.8519227871e-08f

// DPP cross-lane move within 16-lane rows (VALU pipe, not LDS).
// ROW_ROR:N ctrl = 0x120+N. Direction-insensitive uses only (rotations for
// bijective visitation / full-row reductions).
template <int CTRL>
__device__ __forceinline__ float dpp_rot(float v) {
    int i = __float_as_int(v);
    int r = __builtin_amdgcn_update_dpp(i, i, CTRL, 0xF, 0xF, false);
    return __int_as_float(r);
}
template <int CTRL>
__device__ __forceinline__ int dpp_rot_i(int v) {
    return __builtin_amdgcn_update_dpp(v, v, CTRL, 0xF, 0xF, false);
}
// full sum over each 16-lane row, result in every lane of the row
__device__ __forceinline__ float row16_sum(float x) {
    x += dpp_rot<0x128>(x);
    x += dpp_rot<0x124>(x);
    x += dpp_rot<0x122>(x);
    x += dpp_rot<0x121>(x);
    return x;
}

__global__ __launch_bounds__(256) void manifold_render_kernel(
    const float* __restrict__ rays_o, const float* __restrict__ rays_d,
    const float* __restrict__ levels, const float* __restrict__ W1,
    const float* __restrict__ b1, const float* __restrict__ W2,
    const float* __restrict__ b2, float* __restrict__ out, int N)
{
    // per-wave {A2_h, B2_h, -2*w2_h, 0} quads: y_h(t) = A2_h + t*B2_h
    __shared__ float4 abq[4][Hh];

    const int tid = threadIdx.x;
    const int wave = tid >> 6;
    const int lane = tid & 63;
    const int r = blockIdx.x * 4 + wave;
    const bool ray_ok = (r < N);

    const float b2v = b2[0];
    float lvl[Lc];
#pragma unroll
    for (int j = 0; j < Lc; ++j) lvl[j] = levels[j];

    float ox = 0.f, oy = 0.f, oz = 0.f, dx = 0.f, dy = 0.f, dz = 1.f;
    if (ray_ok) {
        ox = rays_o[3 * r]; oy = rays_o[3 * r + 1]; oz = rays_o[3 * r + 2];
        dx = rays_d[3 * r]; dy = rays_d[3 * r + 1]; dz = rays_d[3 * r + 2];
    }

    // per-ray linearization, lane h = lane; fold C into A,B; fold -2 into w2
    float w2lane;
    {
        const float w1x = W1[lane], w1y = W1[Hh + lane], w1z = W1[2 * Hh + lane];
        w2lane = W2[lane];
        const float Ah = __builtin_fmaf(oz, w1z, __builtin_fmaf(oy, w1y,
                         __builtin_fmaf(ox, w1x, b1[lane])));
        const float Bh = __builtin_fmaf(dz, w1z, __builtin_fmaf(dy, w1y, dx * w1x));
        const float A2 = __builtin_fmaf(Ah, C_LO, Ah * C_HI);
        const float B2 = __builtin_fmaf(Bh, C_LO, Bh * C_HI);
        abq[wave][lane] = make_float4(A2, B2, -2.0f * w2lane, 0.0f);
    }
    // Sum(w2) across wave (ray-independent): butterfly
    float w2sum = w2lane;
#pragma unroll
    for (int m = 1; m < 64; m <<= 1) w2sum += __shfl_xor(w2sum, m);
    const float sbase = w2sum + b2v + R0f;

    __syncthreads();
    if (!ray_ok) return;

    // sphere bounds
    const float bq = ox * dx + oy * dy + oz * dz;
    const float cq = ox * ox + oy * oy + oz * oz - R_SPHEREf * R_SPHEREf;
    const float disc = bq * bq - cq;
    const bool hit = disc > 0.0f;
    const float sq = sqrtf(hit ? disc : 1.0f);
    const float d_near = fmaxf(-bq - sq, NEARf);
    const float d_far  = fminf(-bq + sq, FARf);
    const bool mask_bound = hit && (d_near < d_far);

    // ---- sampling: lane = sample index ----
    const float t = (float)lane / (float)(Sn - 1);
    const float dsv = d_near * (1.0f - t) + d_far * t;
    const float x0 = ox + dx * dsv, x1 = oy + dy * dsv, x2 = oz + dz * dsv;
    const float nrm = sqrtf(x0 * x0 + x1 * x1 + x2 * x2);

    const float4* __restrict__ ab = &abq[wave][0];
    const int Rrow = lane >> 4;       // row (0..3)
    const int s16 = lane & 15;        // sublane within row

    // 4 row-start quads (only LDS reads of the main loop). 16B stride across
    // sublanes -> 2-way bank aliasing per phase = free (m136).
    float4 qq[4];
#pragma unroll
    for (int k = 0; k < 4; ++k) qq[k] = ab[(((Rrow + k) & 3) << 4) + s16];

    float acc = 0.0f;
#pragma unroll
    for (int k = 0; k < 4; ++k) {
        float cA = qq[k].x, cB = qq[k].y, cW = qq[k].z;
#pragma unroll
        for (int i = 0; i < 16; ++i) {
            const float y = __builtin_fmaf(dsv, cB, cA);
            const float e = __builtin_amdgcn_exp2f(y);
            const float r1 = __builtin_amdgcn_rcpf(e + 1.0f);
            acc = __builtin_fmaf(cW, r1, acc);
            if (i < 15) {               // rotate coeffs within row (VALU DPP)
                cA = dpp_rot<0x121>(cA);
                cB = dpp_rot<0x121>(cB);
                cW = dpp_rot<0x121>(cW);
            }
        }
    }
    const float scal = (acc + sbase) - nrm;
    const bool valid = nrm < R_SPHEREf;

    // neighbors (back sample of interval at lane j is sample j+1)
    const float scb = __shfl_down(scal, 1);
    const int validn = __shfl_down((int)valid, 1);
    const bool is_int = lane < (Sn - 1);

    // ind_lowest: first-occurrence argmin of sc_b. Within-row via DPP
    // rotation-reduction, cross-row via shfl_xor 16/32. Lexicographic min is
    // assoc+comm, so rotation order is fine.
    float keyv = is_int ? scb : INFINITY;
    int keyi = lane;
#define ARGMIN_STEP_DPP(CTRL)                                            \
    { float ov = dpp_rot<CTRL>(keyv); int oi = dpp_rot_i<CTRL>(keyi);    \
      if (ov < keyv || (ov == keyv && oi < keyi)) { keyv = ov; keyi = oi; } }
    ARGMIN_STEP_DPP(0x128)
    ARGMIN_STEP_DPP(0x124)
    ARGMIN_STEP_DPP(0x122)
    ARGMIN_STEP_DPP(0x121)
#undef ARGMIN_STEP_DPP
#pragma unroll
    for (int m = 16; m < 64; m <<= 1) {
        float ov = __shfl_xor(keyv, m);
        int oi = __shfl_xor(keyi, m);
        if (ov < keyv || (ov == keyv && oi < keyi)) { keyv = ov; keyi = oi; }
    }
    const int ind_lowest = keyi;

    const bool inint_base = is_int && valid && (validn != 0);

    // per-level interval pick + secant init
    bool mintb[Lc], msec[Lc];
    float dinit[Lc];
    float g_dfs = 0.f, g_dbs = 0.f, g_sfs = 0.f, g_sbs = 0.f, g_dcur = 0.f, g_lr = 0.f;
    const int g = lane >> 4;

#pragma unroll
    for (int lv = 0; lv < Lc; ++lv) {
        const float l = lvl[lv];
        unsigned long long bP = __ballot(is_int && (scb < l));
        unsigned long long bZ = __ballot(is_int && (scb == l));
        unsigned long long bI = __ballot(inint_base && (scal >= l) && (l >= scb));
        int ind_closest = bP ? __builtin_ctzll(bP)
                             : (bZ ? __builtin_ctzll(bZ) : (Sn - 2));
        bool mask_surface = (bI != 0ULL);
        int idx = mask_surface ? ind_closest : ind_lowest;

        float d_front = __shfl(dsv, idx);
        float d_back  = __shfl(dsv, idx + 1);
        float s_front = __shfl(scal, idx);
        float s_back  = __shfl(scal, idx + 1);

        bool mi = (s_front >= l) && (l >= s_back);
        float sd = s_front - s_back;
        bool vd = fabsf(sd) > EPSf;
        bool ms = mi && vd;
        float d_sec = ((l - s_back) * d_front + (s_front - l) * d_back) / (vd ? sd : 1.0f);
        float di = ms ? d_sec : d_back;

        mintb[lv] = mi; msec[lv] = ms; dinit[lv] = di;
        if (g == lv) {
            g_dfs = d_front; g_dbs = d_back; g_sfs = s_front; g_sbs = s_back;
            g_dcur = di; g_lr = l;
        }
    }

    // ---- secant refinement: 16 lanes per level, 4 hidden units per lane ----
    const int sub = lane & 15;
    float4 sq0 = ab[sub], sq1 = ab[sub + 16], sq2 = ab[sub + 32], sq3 = ab[sub + 48];

#pragma unroll
    for (int it = 0; it < SECANT_STEPS; ++it) {
        float mx0 = ox + g_dcur * dx, mx1 = oy + g_dcur * dy, mx2 = oz + g_dcur * dz;
        float mn = sqrtf(mx0 * mx0 + mx1 * mx1 + mx2 * mx2);
        float part;
        {
            float y0 = __builtin_fmaf(g_dcur, sq0.y, sq0.x);
            float y1 = __builtin_fmaf(g_dcur, sq1.y, sq1.x);
            float y2 = __builtin_fmaf(g_dcur, sq2.y, sq2.x);
            float y3 = __builtin_fmaf(g_dcur, sq3.y, sq3.x);
            float r0 = __builtin_amdgcn_rcpf(__builtin_amdgcn_exp2f(y0) + 1.0f);
            float r1 = __builtin_amdgcn_rcpf(__builtin_amdgcn_exp2f(y1) + 1.0f);
            float r2 = __builtin_amdgcn_rcpf(__builtin_amdgcn_exp2f(y2) + 1.0f);
            float r3 = __builtin_amdgcn_rcpf(__builtin_amdgcn_exp2f(y3) + 1.0f);
            part = sq0.z * r0;
            part = __builtin_fmaf(sq1.z, r1, part);
            part = __builtin_fmaf(sq2.z, r2, part);
            part = __builtin_fmaf(sq3.z, r3, part);
        }
        part = row16_sum(part);                  // DPP, not LDS
        float s_mid = (part + sbase) - mn;
        bool mv = mn < R_SPHEREf;
        bool upf = (s_mid > g_lr) && mv;
        bool upb = (s_mid < g_lr) && mv;
        if (upf) { g_dfs = g_dcur; g_sfs = s_mid; }
        if (upb) { g_dbs = g_dcur; g_sbs = s_mid; }
        float sd2 = g_sfs - g_sbs;
        bool ok = fabsf(sd2) > EPSf;
        if (ok) g_dcur = ((g_lr - g_sbs) * g_dfs + (g_sfs - g_lr) * g_dbs) / sd2;
    }

    // gather per-level results onto every lane
    float v0, v1, v2, v3;
    {
        float dc0 = __shfl(g_dcur, 0);
        float dc1 = __shfl(g_dcur, 16);
        float dc2 = __shfl(g_dcur, 32);
        float dc3 = __shfl(g_dcur, 48);
        v0 = msec[0] ? dc0 : dinit[0];
        v1 = msec[1] ? dc1 : dinit[1];
        v2 = msec[2] ? dc2 : dinit[2];
        v3 = msec[3] ? dc3 : dinit[3];
    }
    int m0 = mintb[0], m1 = mintb[1], m2 = mintb[2], m3 = mintb[3];
    int i0 = 0, i1 = 1, i2 = 2, i3 = 3;

    // stable sort of 4 by (value, original index) — 5-comparator network
#define CSWAP(va, ia, ma, vb, ib, mb)                                    \
    { bool sw = (vb < va) || (vb == va && ib < ia);                      \
      if (sw) { float tv = va; va = vb; vb = tv;                         \
                int ti = ia; ia = ib; ib = ti;                           \
                int tm = ma; ma = mb; mb = tm; } }
    CSWAP(v0, i0, m0, v1, i1, m1);
    CSWAP(v2, i2, m2, v3, i3, m3);
    CSWAP(v0, i0, m0, v2, i2, m2);
    CSWAP(v1, i1, m1, v3, i3, m3);
    CSWAP(v1, i1, m1, v2, i2, m2);
#undef CSWAP

    const long long NL = (long long)N * Lc;
    if (lane < Lc) {
        float dv = (lane == 0) ? v0 : (lane == 1) ? v1 : (lane == 2) ? v2 : v3;
        out[(long long)r * Lc + lane] = mask_bound ? dv : 0.0f;
    } else if (lane < 2 * Lc) {
        int k = lane - Lc;
        int mm = (k == 0) ? m0 : (k == 1) ? m1 : (k == 2) ? m2 : m3;
        out[NL + (long long)r * Lc + k] = (mm && mask_bound) ? 1.0f : 0.0f;
    }
}

extern "C" void kernel_launch(void* const* d_in, const int* in_sizes, int n_in,
                              void* d_out, int out_size, void* d_ws, size_t ws_size,
                              hipStream_t stream) {
    const float* rays_o = (const float*)d_in[0];
    const float* rays_d = (const float*)d_in[1];
    const float* levels = (const float*)d_in[2];
    const float* W1 = (const float*)d_in[3];
    const float* b1 = (const float*)d_in[4];
    const float* W2 = (const float*)d_in[5];
    const float* b2 = (const float*)d_in[6];
    float* out = (float*)d_out;

    const int N = in_sizes[0] / 3;          // B*R rays
    const int blocks = (N + 3) / 4;         // 4 waves (rays) per 256-thread block
    manifold_render_kernel<<<blocks, 256, 0, stream>>>(
        rays_o, rays_d, levels, W1, b1, W2, b2, out, N);
}

// Round 8
// 135.210 us; speedup vs baseline: 1.0610x; 1.0610x over previous
//
#include <hip/hip_runtime.h>
#include <cstdint>

#define R_SPHEREf 3.0f
#define NEARf 0.0f
#define FARf 100.0f
#define SECANT_STEPS 4
#define EPSf 1e-4f
#define R0f 1.0f
#define Hh 64
#define Lc 4
#define Sn 64

// w2*tanh(x) = w2 - 2*w2*r,  r = 1/(exp2(C*x)+1),  C = 2*log2(e) folded into
// the per-ray linearization (A2,B2). Sampling phase exploits y(t)=A2+t*B2
// linear in t with equally spaced t: E_{i+1} = E_i * rho, rho = 2^(B2*dt) —
// one full-rate mul replaces v_exp (~24 cyc issue measured via R1/R3/R5 fit).
// Recurrence restarted from v_exp every 8 samples to cap error at ~1e-6 rel.
// Reciprocal: bithack + 3 Newton (machine precision; E<=2^14 by input bounds
// so den is always a normal positive float — no NaN path).
#define C_HI 2.88539004325866699f
#define C_LO 3.8519227871e-08f

__device__ __forceinline__ float rcp_fr(float den) {
    float g = __int_as_float(0x7EF311C3 - __float_as_int(den));
    g = g * __builtin_fmaf(-den, g, 2.0f);
    g = g * __builtin_fmaf(-den, g, 2.0f);
    g = g * __builtin_fmaf(-den, g, 2.0f);
    return g;
}

__global__ __launch_bounds__(256) void manifold_render_kernel(
    const float* __restrict__ rays_o, const float* __restrict__ rays_d,
    const float* __restrict__ levels, const float* __restrict__ W1,
    const float* __restrict__ b1, const float* __restrict__ W2,
    const float* __restrict__ b2, float* __restrict__ out, int N)
{
    // per-wave {A2_h, B2_h, -2*w2_h, 0} quads (secant phase only)
    __shared__ float4 abq[4][Hh];

    const int tid = threadIdx.x;
    const int wave = tid >> 6;
    const int lane = tid & 63;
    const int r = blockIdx.x * 4 + wave;
    const bool ray_ok = (r < N);

    const float b2v = b2[0];
    float lvl[Lc];
#pragma unroll
    for (int j = 0; j < Lc; ++j) lvl[j] = levels[j];

    float ox = 0.f, oy = 0.f, oz = 0.f, dx = 0.f, dy = 0.f, dz = 1.f;
    if (ray_ok) {
        ox = rays_o[3 * r]; oy = rays_o[3 * r + 1]; oz = rays_o[3 * r + 2];
        dx = rays_d[3 * r]; dy = rays_d[3 * r + 1]; dz = rays_d[3 * r + 2];
    }

    // per-ray linearization, lane h = lane; fold C into A,B; fold -2 into w2
    float A2, B2, m2w2;
    {
        const float w1x = W1[lane], w1y = W1[Hh + lane], w1z = W1[2 * Hh + lane];
        const float w2lane = W2[lane];
        const float Ah = __builtin_fmaf(oz, w1z, __builtin_fmaf(oy, w1y,
                         __builtin_fmaf(ox, w1x, b1[lane])));
        const float Bh = __builtin_fmaf(dz, w1z, __builtin_fmaf(dy, w1y, dx * w1x));
        A2 = __builtin_fmaf(Ah, C_LO, Ah * C_HI);
        B2 = __builtin_fmaf(Bh, C_LO, Bh * C_HI);
        m2w2 = -2.0f * w2lane;
        abq[wave][lane] = make_float4(A2, B2, m2w2, 0.0f);
        // Sum(w2) across wave (ray-independent): butterfly
        float w2sum = w2lane;
#pragma unroll
        for (int m = 1; m < 64; m <<= 1) w2sum += __shfl_xor(w2sum, m);
        // sbase captured below after syncthreads via recompute-free reg
        abq[wave][lane].w = w2sum;   // stash (same value in all lanes)
    }
    __syncthreads();
    const float sbase = abq[wave][0].w + b2v + R0f;
    if (!ray_ok) return;

    // sphere bounds
    const float bq = ox * dx + oy * dy + oz * dz;
    const float cq = ox * ox + oy * oy + oz * oz - R_SPHEREf * R_SPHEREf;
    const float disc = bq * bq - cq;
    const bool hit = disc > 0.0f;
    const float sq = sqrtf(hit ? disc : 1.0f);
    const float d_near = fmaxf(-bq - sq, NEARf);
    const float d_far  = fminf(-bq + sq, FARf);
    const bool mask_bound = hit && (d_near < d_far);

    // ---- sampling phase A: lane = h; geometric recurrence over samples ----
    const float dt = (d_far - d_near) * (1.0f / 63.0f);
    const float rho = __builtin_amdgcn_exp2f(B2 * dt);
    float p[Sn];
#pragma unroll
    for (int b = 0; b < 8; ++b) {
        const float t0 = __builtin_fmaf((float)(8 * b), dt, d_near);
        float E = __builtin_amdgcn_exp2f(__builtin_fmaf(t0, B2, A2));
#pragma unroll
        for (int j = 0; j < 8; ++j) {
            p[8 * b + j] = m2w2 * rcp_fr(E + 1.0f);
            if (j < 7) E *= rho;
        }
    }
    // ---- transpose-reduce: after 6 stages lane i holds sum_h p[h][i] ----
#pragma unroll
    for (int b = 5; b >= 0; --b) {
        const int m = 1 << b;
        const bool hb = (lane & m) != 0;
#pragma unroll
        for (int j = 0; j < m; ++j) {
            const float a = p[j], c = p[j + m];
            const float send = hb ? a : c;
            const float recv = __shfl_xor(send, m);
            const float keep = hb ? c : a;
            p[j] = keep + recv;
        }
    }

    // ---- sampling phase B: lane = sample index ----
    const float t = (float)lane / (float)(Sn - 1);
    const float dsv = d_near * (1.0f - t) + d_far * t;
    const float x0 = ox + dx * dsv, x1 = oy + dy * dsv, x2 = oz + dz * dsv;
    const float nrm = sqrtf(x0 * x0 + x1 * x1 + x2 * x2);
    const float scal = (p[0] + sbase) - nrm;
    const bool valid = nrm < R_SPHEREf;

    // neighbors (back sample of interval at lane j is sample j+1)
    const float scb = __shfl_down(scal, 1);
    const int validn = __shfl_down((int)valid, 1);
    const bool is_int = lane < (Sn - 1);

    // ind_lowest: first-occurrence argmin of sc_b over intervals
    float keyv = is_int ? scb : INFINITY;
    int keyi = lane;
#pragma unroll
    for (int m = 1; m < 64; m <<= 1) {
        float ov = __shfl_xor(keyv, m);
        int oi = __shfl_xor(keyi, m);
        if (ov < keyv || (ov == keyv && oi < keyi)) { keyv = ov; keyi = oi; }
    }
    const int ind_lowest = keyi;

    const bool inint_base = is_int && valid && (validn != 0);

    // per-level interval pick + secant init
    bool mintb[Lc], msec[Lc];
    float dinit[Lc];
    float g_dfs = 0.f, g_dbs = 0.f, g_sfs = 0.f, g_sbs = 0.f, g_dcur = 0.f, g_lr = 0.f;
    const int g = lane >> 4;

#pragma unroll
    for (int lv = 0; lv < Lc; ++lv) {
        const float l = lvl[lv];
        unsigned long long bP = __ballot(is_int && (scb < l));
        unsigned long long bZ = __ballot(is_int && (scb == l));
        unsigned long long bI = __ballot(inint_base && (scal >= l) && (l >= scb));
        int ind_closest = bP ? __builtin_ctzll(bP)
                             : (bZ ? __builtin_ctzll(bZ) : (Sn - 2));
        bool mask_surface = (bI != 0ULL);
        int idx = mask_surface ? ind_closest : ind_lowest;

        float d_front = __shfl(dsv, idx);
        float d_back  = __shfl(dsv, idx + 1);
        float s_front = __shfl(scal, idx);
        float s_back  = __shfl(scal, idx + 1);

        bool mi = (s_front >= l) && (l >= s_back);
        float sd = s_front - s_back;
        bool vd = fabsf(sd) > EPSf;
        bool ms = mi && vd;
        float d_sec = ((l - s_back) * d_front + (s_front - l) * d_back) / (vd ? sd : 1.0f);
        float di = ms ? d_sec : d_back;

        mintb[lv] = mi; msec[lv] = ms; dinit[lv] = di;
        if (g == lv) {
            g_dfs = d_front; g_dbs = d_back; g_sfs = s_front; g_sbs = s_back;
            g_dcur = di; g_lr = l;
        }
    }

    // ---- secant refinement: 16 lanes per level, 4 hidden units per lane ----
    const float4* __restrict__ ab = &abq[wave][0];
    const int sub = lane & 15;
    float4 sq0 = ab[sub], sq1 = ab[sub + 16], sq2 = ab[sub + 32], sq3 = ab[sub + 48];

#pragma unroll
    for (int it = 0; it < SECANT_STEPS; ++it) {
        float mx0 = ox + g_dcur * dx, mx1 = oy + g_dcur * dy, mx2 = oz + g_dcur * dz;
        float mn = sqrtf(mx0 * mx0 + mx1 * mx1 + mx2 * mx2);
        float part;
        {
            float y0 = __builtin_fmaf(g_dcur, sq0.y, sq0.x);
            float y1 = __builtin_fmaf(g_dcur, sq1.y, sq1.x);
            float y2 = __builtin_fmaf(g_dcur, sq2.y, sq2.x);
            float y3 = __builtin_fmaf(g_dcur, sq3.y, sq3.x);
            float r0 = __builtin_amdgcn_rcpf(__builtin_amdgcn_exp2f(y0) + 1.0f);
            float r1 = __builtin_amdgcn_rcpf(__builtin_amdgcn_exp2f(y1) + 1.0f);
            float r2 = __builtin_amdgcn_rcpf(__builtin_amdgcn_exp2f(y2) + 1.0f);
            float r3 = __builtin_amdgcn_rcpf(__builtin_amdgcn_exp2f(y3) + 1.0f);
            part = sq0.z * r0;
            part = __builtin_fmaf(sq1.z, r1, part);
            part = __builtin_fmaf(sq2.z, r2, part);
            part = __builtin_fmaf(sq3.z, r3, part);
        }
#pragma unroll
        for (int m = 1; m < 16; m <<= 1) part += __shfl_xor(part, m, 16);
        float s_mid = (part + sbase) - mn;
        bool mv = mn < R_SPHEREf;
        bool upf = (s_mid > g_lr) && mv;
        bool upb = (s_mid < g_lr) && mv;
        if (upf) { g_dfs = g_dcur; g_sfs = s_mid; }
        if (upb) { g_dbs = g_dcur; g_sbs = s_mid; }
        float sd2 = g_sfs - g_sbs;
        bool ok = fabsf(sd2) > EPSf;
        if (ok) g_dcur = ((g_lr - g_sbs) * g_dfs + (g_sfs - g_lr) * g_dbs) / sd2;
    }

    // gather per-level results onto every lane
    float v0, v1, v2, v3;
    {
        float dc0 = __shfl(g_dcur, 0);
        float dc1 = __shfl(g_dcur, 16);
        float dc2 = __shfl(g_dcur, 32);
        float dc3 = __shfl(g_dcur, 48);
        v0 = msec[0] ? dc0 : dinit[0];
        v1 = msec[1] ? dc1 : dinit[1];
        v2 = msec[2] ? dc2 : dinit[2];
        v3 = msec[3] ? dc3 : dinit[3];
    }
    int m0 = mintb[0], m1 = mintb[1], m2 = mintb[2], m3 = mintb[3];
    int i0 = 0, i1 = 1, i2 = 2, i3 = 3;

    // stable sort of 4 by (value, original index) — 5-comparator network
#define CSWAP(va, ia, ma, vb, ib, mb)                                    \
    { bool sw = (vb < va) || (vb == va && ib < ia);                      \
      if (sw) { float tv = va; va = vb; vb = tv;                         \
                int ti = ia; ia = ib; ib = ti;                           \
                int tm = ma; ma = mb; mb = tm; } }
    CSWAP(v0, i0, m0, v1, i1, m1);
    CSWAP(v2, i2, m2, v3, i3, m3);
    CSWAP(v0, i0, m0, v2, i2, m2);
    CSWAP(v1, i1, m1, v3, i3, m3);
    CSWAP(v1, i1, m1, v2, i2, m2);
#undef CSWAP

    const long long NL = (long long)N * Lc;
    if (lane < Lc) {
        float dv = (lane == 0) ? v0 : (lane == 1) ? v1 : (lane == 2) ? v2 : v3;
        out[(long long)r * Lc + lane] = mask_bound ? dv : 0.0f;
    } else if (lane < 2 * Lc) {
        int k = lane - Lc;
        int mm = (k == 0) ? m0 : (k == 1) ? m1 : (k == 2) ? m2 : m3;
        out[NL + (long long)r * Lc + k] = (mm && mask_bound) ? 1.0f : 0.0f;
    }
}

extern "C" void kernel_launch(void* const* d_in, const int* in_sizes, int n_in,
                              void* d_out, int out_size, void* d_ws, size_t ws_size,
                              hipStream_t stream) {
    const float* rays_o = (const float*)d_in[0];
    const float* rays_d = (const float*)d_in[1];
    const float* levels = (const float*)d_in[2];
    const float* W1 = (const float*)d_in[3];
    const float* b1 = (const float*)d_in[4];
    const float* W2 = (const float*)d_in[5];
    const float* b2 = (const float*)d_in[6];
    float* out = (float*)d_out;

    const int N = in_sizes[0] / 3;          // B*R rays
    const int blocks = (N + 3) / 4;         // 4 waves (rays) per 256-thread block
    manifold_render_kernel<<<blocks, 256, 0, stream>>>(
        rays_o, rays_d, levels, W1, b1, W2, b2, out, N);
}

// Round 9
// 130.366 us; speedup vs baseline: 1.1005x; 1.0372x over previous
//
#include <hip/hip_runtime.h>
#include <cstdint>

#define R_SPHEREf 3.0f
#define NEARf 0.0f
#define FARf 100.0f
#define SECANT_STEPS 4
#define EPSf 1e-4f
#define R0f 1.0f
#define Hh 64
#define Lc 4
#define Sn 64

// w2*tanh(x) = w2 - 2*w2*r,  r = 1/(exp2(C*x)+1),  C = 2*log2(e) folded into
// the per-ray linearization (A2,B2). Sampling uses the geometric recurrence
// E_{i+1} = E_i * rho (rho = 2^(B2*dt)) so one full-rate mul replaces v_exp;
// restart every 8 samples caps drift ~1e-6 (R8 measured absmax 0.0 with this
// exact numerics). R9 change vs R8: samples processed in 8 batches of 8 so
// the register array is q[8], not p[64] (R8 spilled: VGPR=48 vs ~80 needed,
// occupancy 75->48, dur regressed). Reciprocal: bithack + 3 Newton; E stays
// in [2^-30, 2^30] (samples lie in/near the R=3 sphere) — no NaN path.
#define C_HI 2.88539004325866699f
#define C_LO 3.8519227871e-08f

__device__ __forceinline__ float rcp_fr(float den) {
    float g = __int_as_float(0x7EF311C3 - __float_as_int(den));
    g = g * __builtin_fmaf(-den, g, 2.0f);
    g = g * __builtin_fmaf(-den, g, 2.0f);
    g = g * __builtin_fmaf(-den, g, 2.0f);
    return g;
}

__global__ __launch_bounds__(256) void manifold_render_kernel(
    const float* __restrict__ rays_o, const float* __restrict__ rays_d,
    const float* __restrict__ levels, const float* __restrict__ W1,
    const float* __restrict__ b1, const float* __restrict__ W2,
    const float* __restrict__ b2, float* __restrict__ out, int N)
{
    // per-wave {A2_h, B2_h, -2*w2_h, w2sum} quads (secant phase only)
    __shared__ float4 abq[4][Hh];

    const int tid = threadIdx.x;
    const int wave = tid >> 6;
    const int lane = tid & 63;
    const int r = blockIdx.x * 4 + wave;
    const bool ray_ok = (r < N);

    const float b2v = b2[0];
    float lvl[Lc];
#pragma unroll
    for (int j = 0; j < Lc; ++j) lvl[j] = levels[j];

    float ox = 0.f, oy = 0.f, oz = 0.f, dx = 0.f, dy = 0.f, dz = 1.f;
    if (ray_ok) {
        ox = rays_o[3 * r]; oy = rays_o[3 * r + 1]; oz = rays_o[3 * r + 2];
        dx = rays_d[3 * r]; dy = rays_d[3 * r + 1]; dz = rays_d[3 * r + 2];
    }

    // per-ray linearization, lane h = lane; fold C into A,B; fold -2 into w2
    float A2, B2, m2w2;
    {
        const float w1x = W1[lane], w1y = W1[Hh + lane], w1z = W1[2 * Hh + lane];
        const float w2lane = W2[lane];
        const float Ah = __builtin_fmaf(oz, w1z, __builtin_fmaf(oy, w1y,
                         __builtin_fmaf(ox, w1x, b1[lane])));
        const float Bh = __builtin_fmaf(dz, w1z, __builtin_fmaf(dy, w1y, dx * w1x));
        A2 = __builtin_fmaf(Ah, C_LO, Ah * C_HI);
        B2 = __builtin_fmaf(Bh, C_LO, Bh * C_HI);
        m2w2 = -2.0f * w2lane;
        // Sum(w2) across wave (ray-independent): butterfly
        float w2sum = w2lane;
#pragma unroll
        for (int m = 1; m < 64; m <<= 1) w2sum += __shfl_xor(w2sum, m);
        abq[wave][lane] = make_float4(A2, B2, m2w2, w2sum);
    }
    __syncthreads();
    const float sbase = abq[wave][0].w + b2v + R0f;
    if (!ray_ok) return;

    // sphere bounds
    const float bq = ox * dx + oy * dy + oz * dz;
    const float cq = ox * ox + oy * oy + oz * oz - R_SPHEREf * R_SPHEREf;
    const float disc = bq * bq - cq;
    const bool hit = disc > 0.0f;
    const float sq = sqrtf(hit ? disc : 1.0f);
    const float d_near = fmaxf(-bq - sq, NEARf);
    const float d_far  = fminf(-bq + sq, FARf);
    const bool mask_bound = hit && (d_near < d_far);

    // ---- sampling phase A: lane = h; geometric recurrence, 8 batches of 8.
    // After each batch's transpose-reduce every lane holds the full 64-h sum
    // for sample 8b+(lane&7); lane keeps batch b == lane>>3.
    const float dt = (d_far - d_near) * (1.0f / 63.0f);
    const float rho = __builtin_amdgcn_exp2f(B2 * dt);
    float scal_p = 0.0f;
#pragma unroll
    for (int b = 0; b < 8; ++b) {
        const float t0 = __builtin_fmaf((float)(8 * b), dt, d_near);
        float E = __builtin_amdgcn_exp2f(__builtin_fmaf(t0, B2, A2));
        float q[8];
#pragma unroll
        for (int j = 0; j < 8; ++j) {
            q[j] = m2w2 * rcp_fr(E + 1.0f);
            if (j < 7) E *= rho;
        }
        // within-8-lane-group transpose-reduce (3 stages)
#pragma unroll
        for (int sb = 2; sb >= 0; --sb) {
            const int m = 1 << sb;
            const bool hb = (lane & m) != 0;
#pragma unroll
            for (int j = 0; j < m; ++j) {
                const float a = q[j], c = q[j + m];
                const float send = hb ? a : c;
                const float recv = __shfl_xor(send, m);
                const float keep = hb ? c : a;
                q[j] = keep + recv;
            }
        }
        // q[0] = sum over this 8-lane group; add the other 7 groups
        float tot = q[0];
        tot += __shfl_xor(tot, 8);
        tot += __shfl_xor(tot, 16);
        tot += __shfl_xor(tot, 32);
        if ((lane >> 3) == b) scal_p = tot;
    }

    // ---- sampling phase B: lane = sample index ----
    const float t = (float)lane / (float)(Sn - 1);
    const float dsv = d_near * (1.0f - t) + d_far * t;
    const float x0 = ox + dx * dsv, x1 = oy + dy * dsv, x2 = oz + dz * dsv;
    const float nrm = sqrtf(x0 * x0 + x1 * x1 + x2 * x2);
    const float scal = (scal_p + sbase) - nrm;
    const bool valid = nrm < R_SPHEREf;

    // neighbors (back sample of interval at lane j is sample j+1)
    const float scb = __shfl_down(scal, 1);
    const int validn = __shfl_down((int)valid, 1);
    const bool is_int = lane < (Sn - 1);

    // ind_lowest: first-occurrence argmin of sc_b over intervals
    float keyv = is_int ? scb : INFINITY;
    int keyi = lane;
#pragma unroll
    for (int m = 1; m < 64; m <<= 1) {
        float ov = __shfl_xor(keyv, m);
        int oi = __shfl_xor(keyi, m);
        if (ov < keyv || (ov == keyv && oi < keyi)) { keyv = ov; keyi = oi; }
    }
    const int ind_lowest = keyi;

    const bool inint_base = is_int && valid && (validn != 0);

    // per-level interval pick + secant init
    bool mintb[Lc], msec[Lc];
    float dinit[Lc];
    float g_dfs = 0.f, g_dbs = 0.f, g_sfs = 0.f, g_sbs = 0.f, g_dcur = 0.f, g_lr = 0.f;
    const int g = lane >> 4;

#pragma unroll
    for (int lv = 0; lv < Lc; ++lv) {
        const float l = lvl[lv];
        unsigned long long bP = __ballot(is_int && (scb < l));
        unsigned long long bZ = __ballot(is_int && (scb == l));
        unsigned long long bI = __ballot(inint_base && (scal >= l) && (l >= scb));
        int ind_closest = bP ? __builtin_ctzll(bP)
                             : (bZ ? __builtin_ctzll(bZ) : (Sn - 2));
        bool mask_surface = (bI != 0ULL);
        int idx = mask_surface ? ind_closest : ind_lowest;

        float d_front = __shfl(dsv, idx);
        float d_back  = __shfl(dsv, idx + 1);
        float s_front = __shfl(scal, idx);
        float s_back  = __shfl(scal, idx + 1);

        bool mi = (s_front >= l) && (l >= s_back);
        float sd = s_front - s_back;
        bool vd = fabsf(sd) > EPSf;
        bool ms = mi && vd;
        float d_sec = ((l - s_back) * d_front + (s_front - l) * d_back) / (vd ? sd : 1.0f);
        float di = ms ? d_sec : d_back;

        mintb[lv] = mi; msec[lv] = ms; dinit[lv] = di;
        if (g == lv) {
            g_dfs = d_front; g_dbs = d_back; g_sfs = s_front; g_sbs = s_back;
            g_dcur = di; g_lr = l;
        }
    }

    // ---- secant refinement: 16 lanes per level, 4 hidden units per lane ----
    const float4* __restrict__ ab = &abq[wave][0];
    const int sub = lane & 15;
    float4 sq0 = ab[sub], sq1 = ab[sub + 16], sq2 = ab[sub + 32], sq3 = ab[sub + 48];

#pragma unroll
    for (int it = 0; it < SECANT_STEPS; ++it) {
        float mx0 = ox + g_dcur * dx, mx1 = oy + g_dcur * dy, mx2 = oz + g_dcur * dz;
        float mn = sqrtf(mx0 * mx0 + mx1 * mx1 + mx2 * mx2);
        float part;
        {
            float y0 = __builtin_fmaf(g_dcur, sq0.y, sq0.x);
            float y1 = __builtin_fmaf(g_dcur, sq1.y, sq1.x);
            float y2 = __builtin_fmaf(g_dcur, sq2.y, sq2.x);
            float y3 = __builtin_fmaf(g_dcur, sq3.y, sq3.x);
            float r0 = __builtin_amdgcn_rcpf(__builtin_amdgcn_exp2f(y0) + 1.0f);
            float r1 = __builtin_amdgcn_rcpf(__builtin_amdgcn_exp2f(y1) + 1.0f);
            float r2 = __builtin_amdgcn_rcpf(__builtin_amdgcn_exp2f(y2) + 1.0f);
            float r3 = __builtin_amdgcn_rcpf(__builtin_amdgcn_exp2f(y3) + 1.0f);
            part = sq0.z * r0;
            part = __builtin_fmaf(sq1.z, r1, part);
            part = __builtin_fmaf(sq2.z, r2, part);
            part = __builtin_fmaf(sq3.z, r3, part);
        }
#pragma unroll
        for (int m = 1; m < 16; m <<= 1) part += __shfl_xor(part, m, 16);
        float s_mid = (part + sbase) - mn;
        bool mv = mn < R_SPHEREf;
        bool upf = (s_mid > g_lr) && mv;
        bool upb = (s_mid < g_lr) && mv;
        if (upf) { g_dfs = g_dcur; g_sfs = s_mid; }
        if (upb) { g_dbs = g_dcur; g_sbs = s_mid; }
        float sd2 = g_sfs - g_sbs;
        bool ok = fabsf(sd2) > EPSf;
        if (ok) g_dcur = ((g_lr - g_sbs) * g_dfs + (g_sfs - g_lr) * g_dbs) / sd2;
    }

    // gather per-level results onto every lane
    float v0, v1, v2, v3;
    {
        float dc0 = __shfl(g_dcur, 0);
        float dc1 = __shfl(g_dcur, 16);
        float dc2 = __shfl(g_dcur, 32);
        float dc3 = __shfl(g_dcur, 48);
        v0 = msec[0] ? dc0 : dinit[0];
        v1 = msec[1] ? dc1 : dinit[1];
        v2 = msec[2] ? dc2 : dinit[2];
        v3 = msec[3] ? dc3 : dinit[3];
    }
    int m0 = mintb[0], m1 = mintb[1], m2 = mintb[2], m3 = mintb[3];
    int i0 = 0, i1 = 1, i2 = 2, i3 = 3;

    // stable sort of 4 by (value, original index) — 5-comparator network
#define CSWAP(va, ia, ma, vb, ib, mb)                                    \
    { bool sw = (vb < va) || (vb == va && ib < ia);                      \
      if (sw) { float tv = va; va = vb; vb = tv;                         \
                int ti = ia; ia = ib; ib = ti;                           \
                int tm = ma; ma = mb; mb = tm; } }
    CSWAP(v0, i0, m0, v1, i1, m1);
    CSWAP(v2, i2, m2, v3, i3, m3);
    CSWAP(v0, i0, m0, v2, i2, m2);
    CSWAP(v1, i1, m1, v3, i3, m3);
    CSWAP(v1, i1, m1, v2, i2, m2);
#undef CSWAP

    const long long NL = (long long)N * Lc;
    if (lane < Lc) {
        float dv = (lane == 0) ? v0 : (lane == 1) ? v1 : (lane == 2) ? v2 : v3;
        out[(long long)r * Lc + lane] = mask_bound ? dv : 0.0f;
    } else if (lane < 2 * Lc) {
        int k = lane - Lc;
        int mm = (k == 0) ? m0 : (k == 1) ? m1 : (k == 2) ? m2 : m3;
        out[NL + (long long)r * Lc + k] = (mm && mask_bound) ? 1.0f : 0.0f;
    }
}

extern "C" void kernel_launch(void* const* d_in, const int* in_sizes, int n_in,
                              void* d_out, int out_size, void* d_ws, size_t ws_size,
                              hipStream_t stream) {
    const float* rays_o = (const float*)d_in[0];
    const float* rays_d = (const float*)d_in[1];
    const float* levels = (const float*)d_in[2];
    const float* W1 = (const float*)d_in[3];
    const float* b1 = (const float*)d_in[4];
    const float* W2 = (const float*)d_in[5];
    const float* b2 = (const float*)d_in[6];
    float* out = (float*)d_out;

    const int N = in_sizes[0] / 3;          // B*R rays
    const int blocks = (N + 3) / 4;         // 4 waves (rays) per 256-thread block
    manifold_render_kernel<<<blocks, 256, 0, stream>>>(
        rays_o, rays_d, levels, W1, b1, W2, b2, out, N);
}